// Round 8
// baseline (55427.539 us; speedup 1.0000x reference)
//
#include <hip/hip_runtime.h>
#include <math.h>

// Problem constants (B=16, T=64, NN=4096, H=1024)
constexpr int kB = 16;
constexpr int kT = 64;
constexpr int kH = 1024;

typedef short bf16x8 __attribute__((ext_vector_type(8)));   // 8 bf16 = 4 VGPR
typedef float floatx4 __attribute__((ext_vector_type(4)));  // MFMA acc
typedef unsigned uintx4 __attribute__((ext_vector_type(4))); // 16B asm payload

// ---------------------------------------------------------------------------
// bf16 convert helpers (unchanged, proven absmax 0.0078125)
// ---------------------------------------------------------------------------
__device__ __forceinline__ unsigned short f2bf_rne(float f) {
    unsigned u = __float_as_uint(f);
    u = u + 0x7FFFu + ((u >> 16) & 1u);
    return (unsigned short)(u >> 16);
}
__device__ __forceinline__ unsigned f2bf_fast_u(float f) {
    return (__float_as_uint(f) + 0x8000u) >> 16;
}
__device__ __forceinline__ uint4 pack8(const float4 a, const float4 b) {
    uint4 r;
    r.x = f2bf_fast_u(a.x) | (f2bf_fast_u(a.y) << 16);
    r.y = f2bf_fast_u(a.z) | (f2bf_fast_u(a.w) << 16);
    r.z = f2bf_fast_u(b.x) | (f2bf_fast_u(b.y) << 16);
    r.w = f2bf_fast_u(b.z) | (f2bf_fast_u(b.w) << 16);
    return r;
}

// Fast tanh via __expf (clamped). |err| ~1e-6 — below bf16 quantization.
__device__ __forceinline__ float fast_tanh(float x) {
    const float xc = fminf(fmaxf(x, -15.f), 15.f);
    const float e = __expf(2.f * xc);
    return (e - 1.f) / (e + 1.f);
}

// ---------------------------------------------------------------------------
// Intra-XCD (L2-scope) memory ops. Participants are all on ONE XCD: plain
// stores land in the shared L2; loads with sc0 bypass L1 (the only stale
// tier inside an XCD) and read the shared L2. No sc1, no fences — the L2
// IS the coherence point for this communicator.
// NOTE: asm "v" constraints need ext_vector_type payloads (uintx4), not the
// HIP uint4 struct (round-7 compile failure).
// ---------------------------------------------------------------------------
__device__ __forceinline__ void store_dword_l2(unsigned* p, unsigned v) {
    asm volatile("global_store_dword %0, %1, off sc0"
                 :: "v"(p), "v"(v) : "memory");
}
__device__ __forceinline__ void store_dwordx4_l2(void* p, uintx4 v) {
    asm volatile("global_store_dwordx4 %0, %1, off sc0"
                 :: "v"(p), "v"(v) : "memory");
}
__device__ __forceinline__ unsigned load_dword_l2(const unsigned* p) {
    unsigned v;
    asm volatile("global_load_dword %0, %1, off sc0\n\t"
                 "s_waitcnt vmcnt(0)"
                 : "=v"(v) : "v"(p) : "memory");
    return v;
}

__global__ __launch_bounds__(256)
void pack_bf16(const float* __restrict__ src, unsigned short* __restrict__ dst,
               int n4)
{
    const int i = blockIdx.x * 256 + threadIdx.x;
    if (i < n4) {
        const float4 v = ((const float4*)src)[i];
        ushort4 o;
        o.x = f2bf_rne(v.x); o.y = f2bf_rne(v.y);
        o.z = f2bf_rne(v.z); o.w = f2bf_rne(v.w);
        ((ushort4*)dst)[i] = o;
    }
}

// ---------------------------------------------------------------------------
// 64x64-tile fp32 GEMM (decoder only; M=16 guard): C = X@W^T + bias
// ---------------------------------------------------------------------------
#define GBM 64
#define GBN 64
#define GBK 16
#define GPAD 4

__global__ __launch_bounds__(256)
void gemm_nt_bias(const float* __restrict__ X, const float* __restrict__ W,
                  const float* __restrict__ bias, float* __restrict__ C,
                  int M, int N, int K)
{
    __shared__ float Xs[GBK][GBM + GPAD];
    __shared__ float Ws[GBK][GBN + GPAD];

    const int tid = threadIdx.x;
    const int bm = blockIdx.y * GBM;
    const int bn = blockIdx.x * GBN;
    const int tm = (tid >> 4) * 4;
    const int tn = (tid & 15) * 4;
    const int lr = tid >> 2;
    const int lc = (tid & 3) * 4;

    float acc[4][4] = {};

    for (int k0 = 0; k0 < K; k0 += GBK) {
        {
            const int gr = bm + lr;
            float4 v = make_float4(0.f, 0.f, 0.f, 0.f);
            if (gr < M) v = *(const float4*)(X + (long)gr * K + k0 + lc);
            Xs[lc + 0][lr] = v.x; Xs[lc + 1][lr] = v.y;
            Xs[lc + 2][lr] = v.z; Xs[lc + 3][lr] = v.w;
        }
        {
            const int gr = bn + lr;
            const float4 v = *(const float4*)(W + (long)gr * K + k0 + lc);
            Ws[lc + 0][lr] = v.x; Ws[lc + 1][lr] = v.y;
            Ws[lc + 2][lr] = v.z; Ws[lc + 3][lr] = v.w;
        }
        __syncthreads();
        #pragma unroll
        for (int k = 0; k < GBK; ++k) {
            const float4 a4 = *(const float4*)&Xs[k][tm];
            const float4 b4 = *(const float4*)&Ws[k][tn];
            acc[0][0] += a4.x * b4.x; acc[0][1] += a4.x * b4.y; acc[0][2] += a4.x * b4.z; acc[0][3] += a4.x * b4.w;
            acc[1][0] += a4.y * b4.x; acc[1][1] += a4.y * b4.y; acc[1][2] += a4.y * b4.z; acc[1][3] += a4.y * b4.w;
            acc[2][0] += a4.z * b4.x; acc[2][1] += a4.z * b4.y; acc[2][2] += a4.z * b4.z; acc[2][3] += a4.z * b4.w;
            acc[3][0] += a4.w * b4.x; acc[3][1] += a4.w * b4.y; acc[3][2] += a4.w * b4.z; acc[3][3] += a4.w * b4.w;
        }
        __syncthreads();
    }

    #pragma unroll
    for (int i = 0; i < 4; ++i) {
        const int gr = bm + tm + i;
        if (gr >= M) continue;
        #pragma unroll
        for (int jj = 0; jj < 4; ++jj) {
            const int gc = bn + tn + jj;
            C[(long)gr * N + gc] = acc[i][jj] + bias[gc];
        }
    }
}

// ---------------------------------------------------------------------------
// Phase-A MFMA GEMM (unchanged; next target after the recurrence).
// ---------------------------------------------------------------------------
__global__ __launch_bounds__(256)
void gemm_mfma_a(const float* __restrict__ X,   // [M,K]
                 const float* __restrict__ W,   // [N,K]
                 const float* __restrict__ bias,// [N]
                 float* __restrict__ C,         // [M,N]
                 int M, int N, int K)
{
    __shared__ __attribute__((aligned(16))) unsigned short As[64 * 40];
    __shared__ __attribute__((aligned(16))) unsigned short Bs[128 * 40];

    const int tid  = threadIdx.x;
    const int lane = tid & 63;
    const int w    = tid >> 6;
    const int qm   = w & 1;
    const int qn   = w >> 1;
    const int bm   = blockIdx.y * 64;
    const int bn   = blockIdx.x * 128;
    const int al   = lane & 15;
    const int aq   = lane >> 4;

    floatx4 acc[2][4];
    #pragma unroll
    for (int i = 0; i < 2; ++i)
        #pragma unroll
        for (int j = 0; j < 4; ++j)
            acc[i][j] = (floatx4){0.f, 0.f, 0.f, 0.f};

    const int ar = tid >> 2;
    const int ak = (tid & 3) * 8;

    for (int k0 = 0; k0 < K; k0 += 32) {
        const float* ap = X + (long)(bm + ar) * K + k0 + ak;
        const float4 av0 = *(const float4*)(ap);
        const float4 av1 = *(const float4*)(ap + 4);
        float4 bv0[2], bv1[2];
        #pragma unroll
        for (int l = 0; l < 2; ++l) {
            const int c = tid + 256 * l;
            const float* bp = W + (long)(bn + (c >> 2)) * K + k0 + (c & 3) * 8;
            bv0[l] = *(const float4*)(bp);
            bv1[l] = *(const float4*)(bp + 4);
        }
        __syncthreads();
        *(uint4*)&As[ar * 40 + ak] = pack8(av0, av1);
        #pragma unroll
        for (int l = 0; l < 2; ++l) {
            const int c = tid + 256 * l;
            *(uint4*)&Bs[(c >> 2) * 40 + (c & 3) * 8] = pack8(bv0[l], bv1[l]);
        }
        __syncthreads();

        bf16x8 a[2], b[4];
        #pragma unroll
        for (int i = 0; i < 2; ++i)
            a[i] = *(const bf16x8*)&As[(qm * 32 + i * 16 + al) * 40 + aq * 8];
        #pragma unroll
        for (int j = 0; j < 4; ++j)
            b[j] = *(const bf16x8*)&Bs[(qn * 64 + j * 16 + al) * 40 + aq * 8];
        #pragma unroll
        for (int i = 0; i < 2; ++i)
            #pragma unroll
            for (int j = 0; j < 4; ++j)
                acc[i][j] = __builtin_amdgcn_mfma_f32_16x16x32_bf16(
                    a[i], b[j], acc[i][j], 0, 0, 0);
    }

    #pragma unroll
    for (int i = 0; i < 2; ++i) {
        #pragma unroll
        for (int j = 0; j < 4; ++j) {
            const int row0 = bm + qm * 32 + i * 16 + aq * 4;
            const int col  = bn + qn * 64 + j * 16 + al;
            const float bv = bias[col];
            #pragma unroll
            for (int r = 0; r < 4; ++r)
                C[(long)(row0 + r) * N + col] = acc[i][j][r] + bv;
        }
    }
}

// ---------------------------------------------------------------------------
// PERSISTENT fused GRU v6b — SINGLE-XCD edition.
//
// v4/v5 post-mortem: the step is bound by 4-5 SERIAL system-scope (L3)
// round trips (~2000 cy each). Fix: confine the whole exchange to one
// XCD's L2 (~300 cy RT, intra-XCD coherent once L1 is bypassed via sc0).
//
//  - 32 blocks x 32 columns (weights: wreg[3][2][8] = 192 VGPR/lane).
//  - Launch 256 blocks, LDS padded to 84 KB -> 1 block/CU -> pigeonhole:
//    exactly 32 blocks per XCD. Blocks read HW_REG_XCC_ID; XCD-0 blocks
//    take rank 0..31 (atomicAdd) and participate; others exit.
//  - h buffers block-major [32][16][32] bf16: publish = 1 KB contiguous
//    (16 B/lane, wave 0); A-fragments = 8 contiguous 16 B sc0 loads.
//  - Barrier: plain-store h -> vmcnt(0) -> sc0 flag -> all-poll 32 flags
//    (lane&31) with clock64() timeout-break (hang-proof: bad placement
//    produces a visible absmax failure, never a hang).
// v6b fix: asm payloads use ext_vector_type (uintx4), not uint4 struct.
// ---------------------------------------------------------------------------
#define FLAG_STRIDE 4      // uints; 16 B between flags
#define CNT_IDX     128    // ctrl[128] = rank counter
#define POLL_TIMEOUT 2000000LL

__global__ __launch_bounds__(768, 3)
void fused_gru_persistent(const float* __restrict__ gx0,
                          const unsigned short* __restrict__ w0, const float* __restrict__ bb0,
                          const unsigned short* __restrict__ w1, const float* __restrict__ bb1,
                          const unsigned short* __restrict__ w2, const float* __restrict__ bb2,
                          unsigned short* __restrict__ h1bf0, unsigned short* __restrict__ h1bf1,
                          unsigned short* __restrict__ h2bf0, unsigned short* __restrict__ h2bf1,
                          float* __restrict__ h2last, unsigned* __restrict__ ctrl)
{
    __shared__ __attribute__((aligned(16))) floatx4 part[12][3][2][64]; // 72 KB
    __shared__ __attribute__((aligned(16))) unsigned short h1stage[512]; // [b][j32]
    __shared__ __attribute__((aligned(16))) unsigned short h2stage[512];
    __shared__ char lds_pad[8192];   // forces LDS > 80 KB -> 1 block/CU
    __shared__ int s_role;

    const int tid  = threadIdx.x;    // 0..767
    ((volatile char*)lds_pad)[tid & 8191] = 0;   // keep pad allocated

    // ---- participant selection: first 32 blocks on XCD 0 ----
    if (tid == 0) {
        unsigned xcc;
        asm volatile("s_getreg_b32 %0, hwreg(HW_REG_XCC_ID)" : "=s"(xcc));
        int r = -1;
        if ((xcc & 15u) == 0u)
            r = (int)atomicAdd(&ctrl[CNT_IDX], 1u);
        s_role = (r >= 0 && r < 32) ? r : -1;
    }
    __syncthreads();
    const int role = s_role;
    if (role < 0) return;            // 224 blocks exit

    const int lane  = tid & 63;
    const int wid   = tid >> 6;      // 0..11
    const int jbase = role * 32;

    const int m  = wid >> 2;         // matrix: 0 w_hh0, 1 w_ih1, 2 w_hh1
    const int kh = wid & 3;          // K-quarter
    const int al = lane & 15;
    const int aq = lane >> 4;

    // ---- one-time: weight fragments -> registers (192 VGPR/lane) ----
    const unsigned short* Wm = (m == 0) ? w0 : (m == 1) ? w1 : w2;
    bf16x8 wreg[3][2][8];
    #pragma unroll
    for (int g = 0; g < 3; ++g)
        #pragma unroll
        for (int jt = 0; jt < 2; ++jt)
            #pragma unroll
            for (int s = 0; s < 8; ++s)
                wreg[g][jt][s] = *(const bf16x8*)(
                    Wm + (size_t)g * kH * kH
                       + (size_t)(jbase + jt * 16 + al) * kH
                       + kh * 256 + s * 32 + aq * 8);

    // ---- one-time: update-phase bias preload (tid<512) ----
    const int ub  = tid >> 5;        // batch 0..15
    const int ujj = tid & 31;        // col-in-block 0..31
    const int ujg = jbase + ujj;     // global col
    const float b0r = bb0[ujg], b0z = bb0[kH + ujg], b0n = bb0[2 * kH + ujg];
    const float b1r = bb1[ujg], b1z = bb1[kH + ujg], b1n = bb1[2 * kH + ujg];
    const float b2r = bb2[ujg], b2z = bb2[kH + ujg], b2n = bb2[2 * kH + ujg];

    float h1reg = 0.f;               // h1_{k-1} for this (b,j)
    float h2reg = 0.f;               // h2_{k-2} for this (b,j)

    // update-phase part indices
    const int ujt = ujj >> 4;
    const int pl  = (ub >> 2) * 16 + (ujj & 15);
    const int pr  = ub & 3;

    // publish lane mapping (wave 0): 16 B per lane covers [b=lane>>2][j=(lane&3)*8..+8)
    const int pb = lane >> 2;
    const int pj = (lane & 3) * 8;

    // gx0 for step 0
    float gxr = 0.f, gxz = 0.f, gxn = 0.f;
    if (tid < 512) {
        const float* g = gx0 + (long)ub * (kT * 3 * kH);
        gxr = g[ujg]; gxz = g[kH + ujg]; gxn = g[2 * kH + ujg];
    }

    for (int k = 0; k <= kT; ++k) {
        const unsigned short* h1p = (k & 1) ? h1bf0 : h1bf1;   // h1_{k-1}
        unsigned short*       h1o = (k & 1) ? h1bf1 : h1bf0;   // h1_k
        const unsigned short* h2p = (k & 1) ? h2bf1 : h2bf0;   // h2_{k-2}
        unsigned short*       h2o = (k & 1) ? h2bf0 : h2bf1;   // h2_{k-1}

        // ---- A-fragments: L2-scope loads from block-major bf16 h ----
        const bool azero = (m < 2) ? (k == 0) : (k <= 1);
        const unsigned short* hsrc = (m < 2) ? h1p : h2p;
        bf16x8 a[8];
        if (!azero) {
            #pragma unroll
            for (int s = 0; s < 8; ++s)
                asm volatile("global_load_dwordx4 %0, %1, off sc0"
                             : "=&v"(a[s])
                             : "v"(hsrc + (kh * 8 + s) * 512 + al * 32 + aq * 8)
                             : "memory");
            asm volatile("s_waitcnt vmcnt(0)" ::: "memory");
            __builtin_amdgcn_sched_barrier(0);
        } else {
            #pragma unroll
            for (int s = 0; s < 8; ++s)
                a[s] = (bf16x8){0, 0, 0, 0, 0, 0, 0, 0};
        }

        // ---- 48 MFMAs: 3 gates x 2 col-tiles x 8 k-slices ----
        floatx4 acc[3][2];
        #pragma unroll
        for (int g = 0; g < 3; ++g)
            #pragma unroll
            for (int jt = 0; jt < 2; ++jt)
                acc[g][jt] = (floatx4){0.f, 0.f, 0.f, 0.f};
        #pragma unroll
        for (int s = 0; s < 8; ++s)
            #pragma unroll
            for (int g = 0; g < 3; ++g)
                #pragma unroll
                for (int jt = 0; jt < 2; ++jt)
                    acc[g][jt] = __builtin_amdgcn_mfma_f32_16x16x32_bf16(
                        a[s], wreg[g][jt][s], acc[g][jt], 0, 0, 0);

        #pragma unroll
        for (int g = 0; g < 3; ++g)
            #pragma unroll
            for (int jt = 0; jt < 2; ++jt)
                part[wid][g][jt][lane] = acc[g][jt];   // ds_write_b128
        __syncthreads();

        // ---- cell updates (512 threads: b = tid>>5, j = tid&31) ----
        if (tid < 512) {
            float gh[3][3];
            #pragma unroll
            for (int mm = 0; mm < 3; ++mm)
                #pragma unroll
                for (int g = 0; g < 3; ++g)
                    gh[mm][g] = part[mm * 4 + 0][g][ujt][pl][pr]
                              + part[mm * 4 + 1][g][ujt][pl][pr]
                              + part[mm * 4 + 2][g][ujt][pl][pr]
                              + part[mm * 4 + 3][g][ujt][pl][pr];

            if (k < kT) {   // layer0 step t=k
                const float hr = gh[0][0] + b0r;
                const float hz = gh[0][1] + b0z;
                const float hn = gh[0][2] + b0n;
                const float r = 1.f / (1.f + __expf(-(gxr + hr)));
                const float z = 1.f / (1.f + __expf(-(gxz + hz)));
                const float n = fast_tanh(gxn + r * hn);
                const float hnew = (1.f - z) * n + z * h1reg;
                h1reg = hnew;
                h1stage[tid] = (unsigned short)f2bf_fast_u(hnew);
            }
            if (k > 0) {    // layer1 step t=k-1; gx1 = gh[1] + b_ih1
                const float xr = gh[1][0] + b1r;
                const float xz = gh[1][1] + b1z;
                const float xn = gh[1][2] + b1n;
                const float hr = gh[2][0] + b2r;
                const float hz = gh[2][1] + b2z;
                const float hn = gh[2][2] + b2n;
                const float r = 1.f / (1.f + __expf(-(xr + hr)));
                const float z = 1.f / (1.f + __expf(-(xz + hz)));
                const float n = fast_tanh(xn + r * hn);
                const float hnew = (1.f - z) * n + z * h2reg;
                h2reg = hnew;
                h2stage[tid] = (unsigned short)f2bf_fast_u(hnew);
                if (k == kT) h2last[(long)ub * kH + ujg] = hnew;  // fp32 for decoder
            }
        }

        // ---- prefetch gx0 for step k+1 (hides under barrier) ----
        float nxr = 0.f, nxz = 0.f, nxn = 0.f;
        if (tid < 512 && (k + 1) < kT) {
            const float* g = gx0 + (long)ub * (kT * 3 * kH) + (long)(k + 1) * 3 * kH;
            nxr = g[ujg]; nxz = g[kH + ujg]; nxn = g[2 * kH + ujg];
        }

        // ---- L2-local publish + all-poll barrier ----
        if (k < kT) {
            __syncthreads();          // h stages complete
            if (wid == 0) {
                {
                    const uintx4 v = *(const uintx4*)&h1stage[pb * 32 + pj];
                    store_dwordx4_l2(h1o + role * 512 + pb * 32 + pj, v);
                }
                if (k > 0) {
                    const uintx4 v = *(const uintx4*)&h2stage[pb * 32 + pj];
                    store_dwordx4_l2(h2o + role * 512 + pb * 32 + pj, v);
                }
                asm volatile("s_waitcnt vmcnt(0)" ::: "memory");  // ACKed at L2
                const unsigned gen = (unsigned)(k + 1);
                if (lane == 0)
                    store_dword_l2(&ctrl[role * FLAG_STRIDE], gen);
                // lane i watches flag (i&31); timeout-break makes bad
                // placement a visible failure, never a hang
                const long long t0 = clock64();
                while (load_dword_l2(&ctrl[(lane & 31) * FLAG_STRIDE]) < gen) {
                    if (clock64() - t0 > POLL_TIMEOUT) break;
                }
            }
            __syncthreads();
        }

        gxr = nxr; gxz = nxz; gxn = nxn;
    }
}

// ---------------------------------------------------------------------------
// kernel_launch
// ---------------------------------------------------------------------------
extern "C" void kernel_launch(void* const* d_in, const int* in_sizes, int n_in,
                              void* d_out, int out_size, void* d_ws, size_t ws_size,
                              hipStream_t stream)
{
    const float* x        = (const float*)d_in[0];   // [16,64,4096]
    const float* w_ih_l0  = (const float*)d_in[1];   // [3072,4096]
    const float* w_hh_l0  = (const float*)d_in[2];   // [3072,1024]
    const float* b_ih_l0  = (const float*)d_in[3];   // [3072]
    const float* b_hh_l0  = (const float*)d_in[4];   // [3072]
    const float* w_ih_l1  = (const float*)d_in[5];   // [3072,1024]
    const float* w_hh_l1  = (const float*)d_in[6];   // [3072,1024]
    const float* b_ih_l1  = (const float*)d_in[7];   // [3072]
    const float* b_hh_l1  = (const float*)d_in[8];   // [3072]
    const float* dec_w    = (const float*)d_in[9];   // [4096,1024]
    const float* dec_b    = (const float*)d_in[10];  // [4096]
    float* out = (float*)d_out;                      // [16,4096]

    // Workspace: gx0 12 MB + 4 bf16 h-bufs (block-major) 128 KB +
    // h2last 64 KB + 3 bf16 matrices 18 MB + ctrl (flags+cnt).
    float* ws    = (float*)d_ws;
    float* gx0   = ws;                                  // [1024,3072] rows b*T+t
    unsigned short* h1bf0 = (unsigned short*)(gx0 + (size_t)1024 * 3072);
    unsigned short* h1bf1 = h1bf0 + (size_t)kB * kH;
    unsigned short* h2bf0 = h1bf1 + (size_t)kB * kH;
    unsigned short* h2bf1 = h2bf0 + (size_t)kB * kH;
    float* h2last = (float*)(h2bf1 + (size_t)kB * kH);
    unsigned short* wbf0 = (unsigned short*)(h2last + (size_t)kB * kH);
    unsigned short* wbf1 = wbf0 + (size_t)3 * kH * kH;
    unsigned short* wbf2 = wbf1 + (size_t)3 * kH * kH;
    unsigned* ctrl = (unsigned*)(wbf2 + (size_t)3 * kH * kH);

    // Flags + rank counter must start at 0 each replay.
    (void)hipMemsetAsync(ctrl, 0, 4096, stream);

    const int wn4 = 3 * kH * kH / 4;

    // Pack recurrence weights fp32 -> bf16 (RNE)
    pack_bf16<<<(wn4 + 255) / 256, 256, 0, stream>>>(w_hh_l0, wbf0, wn4);
    pack_bf16<<<(wn4 + 255) / 256, 256, 0, stream>>>(w_ih_l1, wbf1, wn4);
    pack_bf16<<<(wn4 + 255) / 256, 256, 0, stream>>>(w_hh_l1, wbf2, wn4);

    // Phase A (MFMA bf16): gx0 = x @ w_ih_l0^T + b_ih_l0  (M=1024,N=3072,K=4096)
    gemm_mfma_a<<<dim3(3072 / 128, 1024 / 64), 256, 0, stream>>>(
        x, w_ih_l0, b_ih_l0, gx0, 1024, 3072, 4096);

    // Persistent fused recurrence: 256 blocks launched, the 32 on XCD 0
    // participate (1 block/CU forced by 84 KB LDS), rest exit.
    fused_gru_persistent<<<256, 768, 0, stream>>>(
        gx0, wbf0, b_hh_l0, wbf1, b_ih_l1, wbf2, b_hh_l1,
        h1bf0, h1bf1, h2bf0, h2bf1, h2last, ctrl);

    // Decoder (fp32): out = h2_last @ dec_w^T + dec_b  (M=16,N=4096,K=1024)
    gemm_nt_bias<<<dim3(4096 / GBN, 1), 256, 0, stream>>>(
        h2last, dec_w, dec_b, out, kB, 4096, 1024);
}

// Round 9
// 670.450 us; speedup vs baseline: 82.6722x; 82.6722x over previous
//
#include <hip/hip_runtime.h>
#include <math.h>

// Problem constants (B=16, T=64, NN=4096, H=1024)
constexpr int kB = 16;
constexpr int kT = 64;
constexpr int kH = 1024;

typedef short bf16x8 __attribute__((ext_vector_type(8)));   // 8 bf16 = 4 VGPR
typedef float floatx4 __attribute__((ext_vector_type(4)));  // MFMA acc

// ---------------------------------------------------------------------------
// bf16 convert helpers
// ---------------------------------------------------------------------------
__device__ __forceinline__ unsigned short f2bf_rne(float f) {
    unsigned u = __float_as_uint(f);
    u = u + 0x7FFFu + ((u >> 16) & 1u);
    return (unsigned short)(u >> 16);
}
__device__ __forceinline__ unsigned f2bf_fast_u(float f) {
    return (__float_as_uint(f) + 0x8000u) >> 16;
}

// ---------------------------------------------------------------------------
// System-scope (coherence-point) ops — v4 proven. sc0 sc1 = scope 11.
// (v6 lesson: sc0 alone is SE scope — NOT visible across the device.)
// ---------------------------------------------------------------------------
__device__ __forceinline__ void store_short_sys(unsigned short* p, unsigned v) {
    asm volatile("global_store_short %0, %1, off sc0 sc1"
                 :: "v"(p), "v"(v) : "memory");
}
__device__ __forceinline__ void store_dword_sys(unsigned* p, unsigned v) {
    asm volatile("global_store_dword %0, %1, off sc0 sc1"
                 :: "v"(p), "v"(v) : "memory");
}
__device__ __forceinline__ unsigned load_dword_sys(const unsigned* p) {
    unsigned v;
    asm volatile("global_load_dword %0, %1, off sc0 sc1\n\t"
                 "s_waitcnt vmcnt(0)"
                 : "=v"(v) : "v"(p) : "memory");
    return v;
}

// async global->LDS, 16 B per lane (m97 lever). LDS dest must be
// wave-uniform base; lanes land at base + lane*16.
__device__ __forceinline__ void gload_lds16(const unsigned short* g,
                                            unsigned short* lds) {
    __builtin_amdgcn_global_load_lds(
        (const __attribute__((address_space(1))) unsigned int*)(g),
        (__attribute__((address_space(3))) unsigned int*)(lds), 16, 0, 0);
}

__global__ __launch_bounds__(256)
void pack_bf16(const float* __restrict__ src, unsigned short* __restrict__ dst,
               int n4)
{
    const int i = blockIdx.x * 256 + threadIdx.x;
    if (i < n4) {
        const float4 v = ((const float4*)src)[i];
        ushort4 o;
        o.x = f2bf_rne(v.x); o.y = f2bf_rne(v.y);
        o.z = f2bf_rne(v.z); o.w = f2bf_rne(v.w);
        ((ushort4*)dst)[i] = o;
    }
}

// ---------------------------------------------------------------------------
// 64x64-tile fp32 GEMM (decoder only; M=16 guard): C = X@W^T + bias
// ---------------------------------------------------------------------------
#define GBM 64
#define GBN 64
#define GBK 16
#define GPAD 4

__global__ __launch_bounds__(256)
void gemm_nt_bias(const float* __restrict__ X, const float* __restrict__ W,
                  const float* __restrict__ bias, float* __restrict__ C,
                  int M, int N, int K)
{
    __shared__ float Xs[GBK][GBM + GPAD];
    __shared__ float Ws[GBK][GBN + GPAD];

    const int tid = threadIdx.x;
    const int bm = blockIdx.y * GBM;
    const int bn = blockIdx.x * GBN;
    const int tm = (tid >> 4) * 4;
    const int tn = (tid & 15) * 4;
    const int lr = tid >> 2;
    const int lc = (tid & 3) * 4;

    float acc[4][4] = {};

    for (int k0 = 0; k0 < K; k0 += GBK) {
        {
            const int gr = bm + lr;
            float4 v = make_float4(0.f, 0.f, 0.f, 0.f);
            if (gr < M) v = *(const float4*)(X + (long)gr * K + k0 + lc);
            Xs[lc + 0][lr] = v.x; Xs[lc + 1][lr] = v.y;
            Xs[lc + 2][lr] = v.z; Xs[lc + 3][lr] = v.w;
        }
        {
            const int gr = bn + lr;
            const float4 v = *(const float4*)(W + (long)gr * K + k0 + lc);
            Ws[lc + 0][lr] = v.x; Ws[lc + 1][lr] = v.y;
            Ws[lc + 2][lr] = v.z; Ws[lc + 3][lr] = v.w;
        }
        __syncthreads();
        #pragma unroll
        for (int k = 0; k < GBK; ++k) {
            const float4 a4 = *(const float4*)&Xs[k][tm];
            const float4 b4 = *(const float4*)&Ws[k][tn];
            acc[0][0] += a4.x * b4.x; acc[0][1] += a4.x * b4.y; acc[0][2] += a4.x * b4.z; acc[0][3] += a4.x * b4.w;
            acc[1][0] += a4.y * b4.x; acc[1][1] += a4.y * b4.y; acc[1][2] += a4.y * b4.z; acc[1][3] += a4.y * b4.w;
            acc[2][0] += a4.z * b4.x; acc[2][1] += a4.z * b4.y; acc[2][2] += a4.z * b4.z; acc[2][3] += a4.z * b4.w;
            acc[3][0] += a4.w * b4.x; acc[3][1] += a4.w * b4.y; acc[3][2] += a4.w * b4.z; acc[3][3] += a4.w * b4.w;
        }
        __syncthreads();
    }

    #pragma unroll
    for (int i = 0; i < 4; ++i) {
        const int gr = bm + tm + i;
        if (gr >= M) continue;
        #pragma unroll
        for (int jj = 0; jj < 4; ++jj) {
            const int gc = bn + tn + jj;
            C[(long)gr * N + gc] = acc[i][jj] + bias[gc];
        }
    }
}

// ---------------------------------------------------------------------------
// Phase-A GEMM v2 (m97 structure): C[M,N] = X[M,K]@W[N,K]^T + bias.
// bf16 inputs (pre-packed RNE), fp32 out. 128x128x32 tile, 4 waves,
// linear LDS, global_load_lds width=16, 2-barrier K-loop.
// Wave w -> 64x64 quadrant (wm=w&1, wn=w>>1), 4x4 frags of 16x16x32.
// MFMA layouts (m89-verified): A[m=al][k=aq*8+j], B[n=al][k=aq*8+j],
// D[row=aq*4+r][col=al].
// ---------------------------------------------------------------------------
__global__ __launch_bounds__(256)
void gemm_bf16_a(const unsigned short* __restrict__ X,  // [M,K] bf16
                 const unsigned short* __restrict__ W,  // [N,K] bf16
                 const float* __restrict__ bias,        // [N]
                 float* __restrict__ C,                 // [M,N] fp32
                 int M, int N, int K)
{
    __shared__ __attribute__((aligned(16))) unsigned short As[128 * 32];
    __shared__ __attribute__((aligned(16))) unsigned short Bs[128 * 32];

    const int tid  = threadIdx.x;
    const int lane = tid & 63;
    const int w    = tid >> 6;       // 0..3
    const int wm   = w & 1;
    const int wn   = w >> 1;
    const int bm   = blockIdx.y * 128;
    const int bn   = blockIdx.x * 128;
    const int al   = lane & 15;
    const int aq   = lane >> 4;

    // staging: wave w, issue i covers LDS rows [(w*2+i)*16, +16);
    // lane l -> row +(l>>2), col elements (l&3)*8 (16 B).
    const int srow = lane >> 2;          // 0..15
    const int scol = (lane & 3) * 8;     // 0,8,16,24

    floatx4 acc[4][4];
    #pragma unroll
    for (int i = 0; i < 4; ++i)
        #pragma unroll
        for (int j = 0; j < 4; ++j)
            acc[i][j] = (floatx4){0.f, 0.f, 0.f, 0.f};

    for (int k0 = 0; k0 < K; k0 += 32) {
        #pragma unroll
        for (int i = 0; i < 2; ++i) {
            const int r = (w * 2 + i) * 16 + srow;
            gload_lds16(X + (size_t)(bm + r) * K + k0 + scol,
                        As + (w * 2 + i) * 512);
            gload_lds16(W + (size_t)(bn + r) * K + k0 + scol,
                        Bs + (w * 2 + i) * 512);
        }
        __syncthreads();   // drains vmcnt: LDS tile complete

        bf16x8 af[4], bf[4];
        #pragma unroll
        for (int i = 0; i < 4; ++i)
            af[i] = *(const bf16x8*)&As[(wm * 64 + i * 16 + al) * 32 + aq * 8];
        #pragma unroll
        for (int j = 0; j < 4; ++j)
            bf[j] = *(const bf16x8*)&Bs[(wn * 64 + j * 16 + al) * 32 + aq * 8];
        #pragma unroll
        for (int i = 0; i < 4; ++i)
            #pragma unroll
            for (int j = 0; j < 4; ++j)
                acc[i][j] = __builtin_amdgcn_mfma_f32_16x16x32_bf16(
                    af[i], bf[j], acc[i][j], 0, 0, 0);
        __syncthreads();   // readers done before next tile overwrites
    }

    #pragma unroll
    for (int i = 0; i < 4; ++i) {
        #pragma unroll
        for (int j = 0; j < 4; ++j) {
            const int row0 = bm + wm * 64 + i * 16 + aq * 4;
            const int col  = bn + wn * 64 + j * 16 + al;
            const float bv = bias[col];
            #pragma unroll
            for (int r = 0; r < 4; ++r)
                C[(long)(row0 + r) * N + col] = acc[i][j][r] + bv;
        }
    }
}

// ---------------------------------------------------------------------------
// PERSISTENT fused pipelined GRU — v4 VERBATIM (proven 365 us, absmax
// 0.0078125). One launch, 65 in-kernel steps; all cross-block state at
// system scope (sc0 sc1); distributed-flag all-poll barrier.
// (v6's single-XCD attempt is falsified: sc0 alone = SE scope.)
// ---------------------------------------------------------------------------
#define FLAG_STRIDE 4   // uints; 16 B between flags

__global__ __launch_bounds__(768, 3)
void fused_gru_persistent(const float* __restrict__ gx0,
                          const unsigned short* __restrict__ w0, const float* __restrict__ bb0,
                          const unsigned short* __restrict__ w1, const float* __restrict__ bb1,
                          const unsigned short* __restrict__ w2, const float* __restrict__ bb2,
                          unsigned short* __restrict__ h1bf0, unsigned short* __restrict__ h1bf1,
                          unsigned short* __restrict__ h2bf0, unsigned short* __restrict__ h2bf1,
                          float* __restrict__ h2last, unsigned* __restrict__ flags)
{
    __shared__ __attribute__((aligned(16))) floatx4 part[12][3][64]; // [wid][g][lane]

    const int tid   = threadIdx.x;     // 0..767
    const int lane  = tid & 63;
    const int wid   = tid >> 6;        // 0..11
    const int bx    = blockIdx.x;
    const int jbase = bx * 16;

    const int m  = wid >> 2;           // matrix: 0 w_hh0, 1 w_ih1, 2 w_hh1
    const int kh = wid & 3;            // K-quarter
    const int al = lane & 15;
    const int aq = lane >> 4;

    // ---- one-time: weight fragments -> registers ----
    const unsigned short* Wm = (m == 0) ? w0 : (m == 1) ? w1 : w2;
    const long wbase = (long)(jbase + al) * kH + kh * 256 + aq * 8;
    bf16x8 wreg[3][8];
    #pragma unroll
    for (int g = 0; g < 3; ++g)
        #pragma unroll
        for (int s = 0; s < 8; ++s)
            wreg[g][s] = *(const bf16x8*)(Wm + (long)g * kH * kH + wbase + s * 32);

    // ---- one-time: update-phase bias preload (tid<256 only) ----
    const int ub  = tid >> 4;          // batch row for update phase
    const int ujj = tid & 15;
    const int ujg = jbase + ujj;
    const float b0r = bb0[ujg], b0z = bb0[kH + ujg], b0n = bb0[2 * kH + ujg];
    const float b1r = bb1[ujg], b1z = bb1[kH + ujg], b1n = bb1[2 * kH + ujg];
    const float b2r = bb2[ujg], b2z = bb2[kH + ujg], b2n = bb2[2 * kH + ujg];

    // per-thread fp32 recursion state (update threads only)
    float h1reg = 0.f;   // h1_{k-1} for this (b,j)
    float h2reg = 0.f;   // h2_{k-2} for this (b,j)

    // A-fragment offset within an h buffer (elements)
    const int aoff = al * kH + kh * 256 + aq * 8;
    const int pl   = (ub >> 2) * 16 + ujj;   // part lane index for update read
    const int pr   = ub & 3;                 // part reg index

    // gx0 for step 0 preloaded (subsequent steps prefetched under barrier)
    float gxr = 0.f, gxz = 0.f, gxn = 0.f;
    if (tid < 256) {
        const float* g = gx0 + (long)ub * (kT * 3 * kH);
        gxr = g[ujg]; gxz = g[kH + ujg]; gxn = g[2 * kH + ujg];
    }

    for (int k = 0; k <= kT; ++k) {
        // ping-pong pointers
        const unsigned short* h1p = (k & 1) ? h1bf0 : h1bf1;   // h1_{k-1}
        unsigned short*       h1o = (k & 1) ? h1bf1 : h1bf0;   // h1_k
        const unsigned short* h2p = (k & 1) ? h2bf1 : h2bf0;   // h2_{k-2}
        unsigned short*       h2o = (k & 1) ? h2bf0 : h2bf1;   // h2_{k-1}

        // ---- A-fragments: system-scope loads from the bf16 h buffers ----
        const bool azero = (m < 2) ? (k == 0) : (k <= 1);
        const unsigned short* hsrc = (m < 2) ? h1p : h2p;
        bf16x8 a[8];
        if (!azero) {
            #pragma unroll
            for (int s = 0; s < 8; ++s)
                asm volatile("global_load_dwordx4 %0, %1, off sc0 sc1"
                             : "=&v"(a[s]) : "v"(hsrc + aoff + s * 32) : "memory");
            asm volatile("s_waitcnt vmcnt(0)" ::: "memory");
            __builtin_amdgcn_sched_barrier(0);
        } else {
            #pragma unroll
            for (int s = 0; s < 8; ++s)
                a[s] = (bf16x8){0, 0, 0, 0, 0, 0, 0, 0};
        }

        // ---- 24 MFMAs (weights + A in registers) ----
        floatx4 acc[3];
        #pragma unroll
        for (int g = 0; g < 3; ++g) acc[g] = (floatx4){0.f, 0.f, 0.f, 0.f};
        #pragma unroll
        for (int s = 0; s < 8; ++s)
            #pragma unroll
            for (int g = 0; g < 3; ++g)
                acc[g] = __builtin_amdgcn_mfma_f32_16x16x32_bf16(
                    a[s], wreg[g][s], acc[g], 0, 0, 0);

        #pragma unroll
        for (int g = 0; g < 3; ++g)
            part[wid][g][lane] = acc[g];     // ds_write_b128, conflict-free
        __syncthreads();

        // ---- cell updates (256 threads: b = tid>>4, j = tid&15) ----
        if (tid < 256) {
            float gh[3][3];
            #pragma unroll
            for (int mm = 0; mm < 3; ++mm)
                #pragma unroll
                for (int g = 0; g < 3; ++g)
                    gh[mm][g] = part[mm * 4 + 0][g][pl][pr] + part[mm * 4 + 1][g][pl][pr]
                              + part[mm * 4 + 2][g][pl][pr] + part[mm * 4 + 3][g][pl][pr];

            if (k < kT) {   // layer0 step t=k
                const float hr = gh[0][0] + b0r;
                const float hz = gh[0][1] + b0z;
                const float hn = gh[0][2] + b0n;
                const float r = 1.f / (1.f + __expf(-(gxr + hr)));
                const float z = 1.f / (1.f + __expf(-(gxz + hz)));
                const float n = tanhf(gxn + r * hn);
                const float hnew = (1.f - z) * n + z * h1reg;
                h1reg = hnew;
                store_short_sys(h1o + ub * kH + ujg, f2bf_fast_u(hnew));
            }
            if (k > 0) {    // layer1 step t=k-1; gx1 = gh[1] + b_ih1
                const float xr = gh[1][0] + b1r;
                const float xz = gh[1][1] + b1z;
                const float xn = gh[1][2] + b1n;
                const float hr = gh[2][0] + b2r;
                const float hz = gh[2][1] + b2z;
                const float hn = gh[2][2] + b2n;
                const float r = 1.f / (1.f + __expf(-(xr + hr)));
                const float z = 1.f / (1.f + __expf(-(xz + hz)));
                const float n = tanhf(xn + r * hn);
                const float hnew = (1.f - z) * n + z * h2reg;
                h2reg = hnew;
                store_short_sys(h2o + ub * kH + ujg, f2bf_fast_u(hnew));
                if (k == kT) h2last[(long)ub * kH + ujg] = hnew;  // fp32 for decoder
            }
        }

        // ---- prefetch gx0 for step k+1 (read-only; hides under barrier) ----
        float nxr = 0.f, nxz = 0.f, nxn = 0.f;
        if (tid < 256 && (k + 1) < kT) {
            const float* g = gx0 + (long)ub * (kT * 3 * kH) + (long)(k + 1) * 3 * kH;
            nxr = g[ujg]; nxz = g[kH + ujg]; nxn = g[2 * kH + ujg];
        }

        // ---- fence-free distributed-flag barrier (all state at L3) ----
        if (k < kT) {
            __syncthreads();          // per-wave vmcnt(0): sc-stores ACKed at L3
            if (wid == 0) {
                const unsigned gen = (unsigned)(k + 1);
                if (lane == 0)
                    store_dword_sys(&flags[bx * FLAG_STRIDE], gen);
                // lane i watches block i's flag
                while (load_dword_sys(&flags[lane * FLAG_STRIDE]) < gen) {}
            }
            __syncthreads();
        }

        gxr = nxr; gxz = nxz; gxn = nxn;
    }
}

// ---------------------------------------------------------------------------
// kernel_launch
// ---------------------------------------------------------------------------
extern "C" void kernel_launch(void* const* d_in, const int* in_sizes, int n_in,
                              void* d_out, int out_size, void* d_ws, size_t ws_size,
                              hipStream_t stream)
{
    const float* x        = (const float*)d_in[0];   // [16,64,4096]
    const float* w_ih_l0  = (const float*)d_in[1];   // [3072,4096]
    const float* w_hh_l0  = (const float*)d_in[2];   // [3072,1024]
    const float* b_ih_l0  = (const float*)d_in[3];   // [3072]
    const float* b_hh_l0  = (const float*)d_in[4];   // [3072]
    const float* w_ih_l1  = (const float*)d_in[5];   // [3072,1024]
    const float* w_hh_l1  = (const float*)d_in[6];   // [3072,1024]
    const float* b_ih_l1  = (const float*)d_in[7];   // [3072]
    const float* b_hh_l1  = (const float*)d_in[8];   // [3072]
    const float* dec_w    = (const float*)d_in[9];   // [4096,1024]
    const float* dec_b    = (const float*)d_in[10];  // [4096]
    float* out = (float*)d_out;                      // [16,4096]

    // Workspace (~62.5 MB): gx0 12 MB + 4 bf16 h-bufs 128 KB + h2last 64 KB
    // + 3 recurrence bf16 matrices 18 MB + xbf 8 MB + wihbf 24 MB + flags.
    float* ws    = (float*)d_ws;
    float* gx0   = ws;                                  // [1024,3072] rows b*T+t
    unsigned short* h1bf0 = (unsigned short*)(gx0 + (size_t)1024 * 3072);
    unsigned short* h1bf1 = h1bf0 + (size_t)kB * kH;
    unsigned short* h2bf0 = h1bf1 + (size_t)kB * kH;
    unsigned short* h2bf1 = h2bf0 + (size_t)kB * kH;
    float* h2last = (float*)(h2bf1 + (size_t)kB * kH);
    unsigned short* wbf0 = (unsigned short*)(h2last + (size_t)kB * kH);
    unsigned short* wbf1 = wbf0 + (size_t)3 * kH * kH;
    unsigned short* wbf2 = wbf1 + (size_t)3 * kH * kH;
    unsigned short* xbf  = wbf2 + (size_t)3 * kH * kH;          // [1024,4096]
    unsigned short* wihbf = xbf + (size_t)1024 * 4096;          // [3072,4096]
    unsigned* flags = (unsigned*)(wihbf + (size_t)3072 * 4096);

    // Flags must start at 0 each replay (memset node in the graph).
    (void)hipMemsetAsync(flags, 0, 4096, stream);

    const int wn4 = 3 * kH * kH / 4;           // 786432
    const int xn4 = 1024 * 4096 / 4;           // 1048576
    const int win4 = 3072 * 4096 / 4;          // 3145728

    // Pack recurrence weights + Phase-A operands fp32 -> bf16 (RNE)
    pack_bf16<<<(wn4 + 255) / 256, 256, 0, stream>>>(w_hh_l0, wbf0, wn4);
    pack_bf16<<<(wn4 + 255) / 256, 256, 0, stream>>>(w_ih_l1, wbf1, wn4);
    pack_bf16<<<(wn4 + 255) / 256, 256, 0, stream>>>(w_hh_l1, wbf2, wn4);
    pack_bf16<<<(xn4 + 255) / 256, 256, 0, stream>>>(x, xbf, xn4);
    pack_bf16<<<(win4 + 255) / 256, 256, 0, stream>>>(w_ih_l0, wihbf, win4);

    // Phase A (m97-style bf16 MFMA): gx0 = x @ w_ih_l0^T + b_ih_l0
    // (M=1024, N=3072, K=4096), 128x128 tile, grid (24, 8).
    gemm_bf16_a<<<dim3(3072 / 128, 1024 / 128), 256, 0, stream>>>(
        xbf, wihbf, b_ih_l0, gx0, 1024, 3072, 4096);

    // Persistent fused recurrence: ONE launch, 65 in-kernel steps (v4).
    fused_gru_persistent<<<64, 768, 0, stream>>>(
        gx0, wbf0, b_hh_l0, wbf1, b_ih_l1, wbf2, b_hh_l1,
        h1bf0, h1bf1, h2bf0, h2bf1, h2last, flags);

    // Decoder (fp32): out = h2_last @ dec_w^T + dec_b  (M=16,N=4096,K=1024)
    gemm_nt_bias<<<dim3(4096 / GBN, 1), 256, 0, stream>>>(
        h2last, dec_w, dec_b, out, kB, 4096, 1024);
}

// Round 10
// 666.396 us; speedup vs baseline: 83.1751x; 1.0061x over previous
//
#include <hip/hip_runtime.h>
#include <math.h>

// Problem constants (B=16, T=64, NN=4096, H=1024)
constexpr int kB = 16;
constexpr int kT = 64;
constexpr int kH = 1024;

typedef short bf16x8 __attribute__((ext_vector_type(8)));   // 8 bf16 = 4 VGPR
typedef float floatx4 __attribute__((ext_vector_type(4)));  // MFMA acc

// ---------------------------------------------------------------------------
// bf16 convert helpers
// ---------------------------------------------------------------------------
__device__ __forceinline__ unsigned short f2bf_rne(float f) {
    unsigned u = __float_as_uint(f);
    u = u + 0x7FFFu + ((u >> 16) & 1u);
    return (unsigned short)(u >> 16);
}
__device__ __forceinline__ unsigned f2bf_fast_u(float f) {
    return (__float_as_uint(f) + 0x8000u) >> 16;
}

// ---------------------------------------------------------------------------
// System-scope (coherence-point) ops — v4 proven. sc0 sc1 = scope 11.
// (v6 lesson: sc0 alone is SE scope — NOT visible across the device.)
// ---------------------------------------------------------------------------
__device__ __forceinline__ void store_short_sys(unsigned short* p, unsigned v) {
    asm volatile("global_store_short %0, %1, off sc0 sc1"
                 :: "v"(p), "v"(v) : "memory");
}
__device__ __forceinline__ void store_dword_sys(unsigned* p, unsigned v) {
    asm volatile("global_store_dword %0, %1, off sc0 sc1"
                 :: "v"(p), "v"(v) : "memory");
}
__device__ __forceinline__ unsigned load_dword_sys(const unsigned* p) {
    unsigned v;
    asm volatile("global_load_dword %0, %1, off sc0 sc1\n\t"
                 "s_waitcnt vmcnt(0)"
                 : "=v"(v) : "v"(p) : "memory");
    return v;
}

// async global->LDS, 16 B per lane. LDS dest is wave-uniform base; lanes
// land at base + lane*16.
__device__ __forceinline__ void gload_lds16(const unsigned short* g,
                                            unsigned short* lds) {
    __builtin_amdgcn_global_load_lds(
        (const __attribute__((address_space(1))) unsigned int*)(g),
        (__attribute__((address_space(3))) unsigned int*)(lds), 16, 0, 0);
}

__global__ __launch_bounds__(256)
void pack_bf16(const float* __restrict__ src, unsigned short* __restrict__ dst,
               int n4)
{
    const int i = blockIdx.x * 256 + threadIdx.x;
    if (i < n4) {
        const float4 v = ((const float4*)src)[i];
        ushort4 o;
        o.x = f2bf_rne(v.x); o.y = f2bf_rne(v.y);
        o.z = f2bf_rne(v.z); o.w = f2bf_rne(v.w);
        ((ushort4*)dst)[i] = o;
    }
}

// ---------------------------------------------------------------------------
// 64x64-tile fp32 GEMM (decoder only; M=16 guard): C = X@W^T + bias
// ---------------------------------------------------------------------------
#define GBM 64
#define GBN 64
#define GBK 16
#define GPAD 4

__global__ __launch_bounds__(256)
void gemm_nt_bias(const float* __restrict__ X, const float* __restrict__ W,
                  const float* __restrict__ bias, float* __restrict__ C,
                  int M, int N, int K)
{
    __shared__ float Xs[GBK][GBM + GPAD];
    __shared__ float Ws[GBK][GBN + GPAD];

    const int tid = threadIdx.x;
    const int bm = blockIdx.y * GBM;
    const int bn = blockIdx.x * GBN;
    const int tm = (tid >> 4) * 4;
    const int tn = (tid & 15) * 4;
    const int lr = tid >> 2;
    const int lc = (tid & 3) * 4;

    float acc[4][4] = {};

    for (int k0 = 0; k0 < K; k0 += GBK) {
        {
            const int gr = bm + lr;
            float4 v = make_float4(0.f, 0.f, 0.f, 0.f);
            if (gr < M) v = *(const float4*)(X + (long)gr * K + k0 + lc);
            Xs[lc + 0][lr] = v.x; Xs[lc + 1][lr] = v.y;
            Xs[lc + 2][lr] = v.z; Xs[lc + 3][lr] = v.w;
        }
        {
            const int gr = bn + lr;
            const float4 v = *(const float4*)(W + (long)gr * K + k0 + lc);
            Ws[lc + 0][lr] = v.x; Ws[lc + 1][lr] = v.y;
            Ws[lc + 2][lr] = v.z; Ws[lc + 3][lr] = v.w;
        }
        __syncthreads();
        #pragma unroll
        for (int k = 0; k < GBK; ++k) {
            const float4 a4 = *(const float4*)&Xs[k][tm];
            const float4 b4 = *(const float4*)&Ws[k][tn];
            acc[0][0] += a4.x * b4.x; acc[0][1] += a4.x * b4.y; acc[0][2] += a4.x * b4.z; acc[0][3] += a4.x * b4.w;
            acc[1][0] += a4.y * b4.x; acc[1][1] += a4.y * b4.y; acc[1][2] += a4.y * b4.z; acc[1][3] += a4.y * b4.w;
            acc[2][0] += a4.z * b4.x; acc[2][1] += a4.z * b4.y; acc[2][2] += a4.z * b4.z; acc[2][3] += a4.z * b4.w;
            acc[3][0] += a4.w * b4.x; acc[3][1] += a4.w * b4.y; acc[3][2] += a4.w * b4.z; acc[3][3] += a4.w * b4.w;
        }
        __syncthreads();
    }

    #pragma unroll
    for (int i = 0; i < 4; ++i) {
        const int gr = bm + tm + i;
        if (gr >= M) continue;
        #pragma unroll
        for (int jj = 0; jj < 4; ++jj) {
            const int gc = bn + tn + jj;
            C[(long)gr * N + gc] = acc[i][jj] + bias[gc];
        }
    }
}

// ---------------------------------------------------------------------------
// Phase-A GEMM v3: C[M,N] = X[M,K]@W[N,K]^T + bias, bf16 in / fp32 out.
// 64(M)x128(N)x32(K) tile -> grid 384 blocks (1.5/CU, XCD-swizzled).
// DEPTH-2 pipeline (T3/T4 minimum): 4 LDS buffers (48 KB); each iter issues
// tile t+2 (3 gload_lds/wave), s_waitcnt vmcnt(6) — counted, never 0 —
// raw s_barrier, ds_read + 8 MFMA/wave, raw s_barrier. WAR on the 4-ring
// is ordered by the collective barriers. K-order identical to v2 ->
// bit-identical results.
// ---------------------------------------------------------------------------
__global__ __launch_bounds__(256)
void gemm_bf16_a(const unsigned short* __restrict__ X,  // [M,K] bf16
                 const unsigned short* __restrict__ W,  // [N,K] bf16
                 const float* __restrict__ bias,        // [N]
                 float* __restrict__ C,                 // [M,N] fp32
                 int M, int N, int K)
{
    __shared__ __attribute__((aligned(16))) unsigned short As[4][64 * 32];  // 4x4KB
    __shared__ __attribute__((aligned(16))) unsigned short Bs[4][128 * 32]; // 4x8KB

    const int tid  = threadIdx.x;
    const int lane = tid & 63;
    const int w    = tid >> 6;       // 0..3
    const int wm   = w & 1;          // 32-row half
    const int wn   = w >> 1;         // 64-col half
    const int al   = lane & 15;
    const int aq   = lane >> 4;

    // XCD swizzle (384 % 8 == 0 -> simple form is bijective)
    const int bid = blockIdx.x;
    const int swz = (bid & 7) * 48 + (bid >> 3);
    const int bn  = (swz % 24) * 128;
    const int bm  = (swz / 24) * 64;

    // staging: lane l -> row l>>2 (16 rows/issue), col elems (l&3)*8
    const int srow = lane >> 2;
    const int scol = (lane & 3) * 8;

    const int nT = K / 32;           // 128

    // issue tile t into ring buffer buf (3 gload_lds per wave)
    #define ISSUE_A(buf, k0c)                                                  \
        gload_lds16(X + (size_t)(bm + w * 16 + srow) * K + (k0c) + scol,       \
                    &As[buf][(w * 16) * 32]);                                  \
        gload_lds16(W + (size_t)(bn + w * 32 + srow) * K + (k0c) + scol,       \
                    &Bs[buf][(w * 32) * 32]);                                  \
        gload_lds16(W + (size_t)(bn + w * 32 + 16 + srow) * K + (k0c) + scol,  \
                    &Bs[buf][(w * 32 + 16) * 32]);

    floatx4 acc[2][4];
    #pragma unroll
    for (int i = 0; i < 2; ++i)
        #pragma unroll
        for (int j = 0; j < 4; ++j)
            acc[i][j] = (floatx4){0.f, 0.f, 0.f, 0.f};

    // prologue: tiles 0,1 in flight (6 loads/wave outstanding)
    ISSUE_A(0, 0);
    ISSUE_A(1, 32);

    for (int t = 0; t < nT; ++t) {
        // issue tile t+2 (clamped dummy re-issue at the tail keeps vmcnt
        // accounting uniform; the target buffer is never read past the end)
        const int k2 = (t + 2 < nT) ? (t + 2) * 32 : t * 32;
        const int b2 = (t + 2) & 3;
        ISSUE_A(b2, k2);

        asm volatile("s_waitcnt vmcnt(6)" ::: "memory");  // tile t complete
        __builtin_amdgcn_s_barrier();                     // ... in all waves
        asm volatile("" ::: "memory");                    // pin reads below

        const int cb = t & 3;
        bf16x8 af[2], bf[4];
        #pragma unroll
        for (int i = 0; i < 2; ++i)
            af[i] = *(const bf16x8*)&As[cb][(wm * 32 + i * 16 + al) * 32 + aq * 8];
        #pragma unroll
        for (int j = 0; j < 4; ++j)
            bf[j] = *(const bf16x8*)&Bs[cb][(wn * 64 + j * 16 + al) * 32 + aq * 8];
        #pragma unroll
        for (int i = 0; i < 2; ++i)
            #pragma unroll
            for (int j = 0; j < 4; ++j)
                acc[i][j] = __builtin_amdgcn_mfma_f32_16x16x32_bf16(
                    af[i], bf[j], acc[i][j], 0, 0, 0);

        asm volatile("" ::: "memory");                    // pin reads above
        __builtin_amdgcn_s_barrier();                     // readers done
    }
    #undef ISSUE_A

    #pragma unroll
    for (int i = 0; i < 2; ++i) {
        #pragma unroll
        for (int j = 0; j < 4; ++j) {
            const int row0 = bm + wm * 32 + i * 16 + aq * 4;
            const int col  = bn + wn * 64 + j * 16 + al;
            const float bv = bias[col];
            #pragma unroll
            for (int r = 0; r < 4; ++r)
                C[(long)(row0 + r) * N + col] = acc[i][j][r] + bv;
        }
    }
}

// ---------------------------------------------------------------------------
// PERSISTENT fused pipelined GRU — v4 VERBATIM (proven 367 us, absmax
// 0.0078125). One launch, 65 in-kernel steps; all cross-block state at
// system scope (sc0 sc1); distributed-flag all-poll barrier.
// ---------------------------------------------------------------------------
#define FLAG_STRIDE 4   // uints; 16 B between flags

__global__ __launch_bounds__(768, 3)
void fused_gru_persistent(const float* __restrict__ gx0,
                          const unsigned short* __restrict__ w0, const float* __restrict__ bb0,
                          const unsigned short* __restrict__ w1, const float* __restrict__ bb1,
                          const unsigned short* __restrict__ w2, const float* __restrict__ bb2,
                          unsigned short* __restrict__ h1bf0, unsigned short* __restrict__ h1bf1,
                          unsigned short* __restrict__ h2bf0, unsigned short* __restrict__ h2bf1,
                          float* __restrict__ h2last, unsigned* __restrict__ flags)
{
    __shared__ __attribute__((aligned(16))) floatx4 part[12][3][64]; // [wid][g][lane]

    const int tid   = threadIdx.x;     // 0..767
    const int lane  = tid & 63;
    const int wid   = tid >> 6;        // 0..11
    const int bx    = blockIdx.x;
    const int jbase = bx * 16;

    const int m  = wid >> 2;           // matrix: 0 w_hh0, 1 w_ih1, 2 w_hh1
    const int kh = wid & 3;            // K-quarter
    const int al = lane & 15;
    const int aq = lane >> 4;

    // ---- one-time: weight fragments -> registers ----
    const unsigned short* Wm = (m == 0) ? w0 : (m == 1) ? w1 : w2;
    const long wbase = (long)(jbase + al) * kH + kh * 256 + aq * 8;
    bf16x8 wreg[3][8];
    #pragma unroll
    for (int g = 0; g < 3; ++g)
        #pragma unroll
        for (int s = 0; s < 8; ++s)
            wreg[g][s] = *(const bf16x8*)(Wm + (long)g * kH * kH + wbase + s * 32);

    // ---- one-time: update-phase bias preload (tid<256 only) ----
    const int ub  = tid >> 4;          // batch row for update phase
    const int ujj = tid & 15;
    const int ujg = jbase + ujj;
    const float b0r = bb0[ujg], b0z = bb0[kH + ujg], b0n = bb0[2 * kH + ujg];
    const float b1r = bb1[ujg], b1z = bb1[kH + ujg], b1n = bb1[2 * kH + ujg];
    const float b2r = bb2[ujg], b2z = bb2[kH + ujg], b2n = bb2[2 * kH + ujg];

    // per-thread fp32 recursion state (update threads only)
    float h1reg = 0.f;   // h1_{k-1} for this (b,j)
    float h2reg = 0.f;   // h2_{k-2} for this (b,j)

    // A-fragment offset within an h buffer (elements)
    const int aoff = al * kH + kh * 256 + aq * 8;
    const int pl   = (ub >> 2) * 16 + ujj;   // part lane index for update read
    const int pr   = ub & 3;                 // part reg index

    // gx0 for step 0 preloaded (subsequent steps prefetched under barrier)
    float gxr = 0.f, gxz = 0.f, gxn = 0.f;
    if (tid < 256) {
        const float* g = gx0 + (long)ub * (kT * 3 * kH);
        gxr = g[ujg]; gxz = g[kH + ujg]; gxn = g[2 * kH + ujg];
    }

    for (int k = 0; k <= kT; ++k) {
        // ping-pong pointers
        const unsigned short* h1p = (k & 1) ? h1bf0 : h1bf1;   // h1_{k-1}
        unsigned short*       h1o = (k & 1) ? h1bf1 : h1bf0;   // h1_k
        const unsigned short* h2p = (k & 1) ? h2bf1 : h2bf0;   // h2_{k-2}
        unsigned short*       h2o = (k & 1) ? h2bf0 : h2bf1;   // h2_{k-1}

        // ---- A-fragments: system-scope loads from the bf16 h buffers ----
        const bool azero = (m < 2) ? (k == 0) : (k <= 1);
        const unsigned short* hsrc = (m < 2) ? h1p : h2p;
        bf16x8 a[8];
        if (!azero) {
            #pragma unroll
            for (int s = 0; s < 8; ++s)
                asm volatile("global_load_dwordx4 %0, %1, off sc0 sc1"
                             : "=&v"(a[s]) : "v"(hsrc + aoff + s * 32) : "memory");
            asm volatile("s_waitcnt vmcnt(0)" ::: "memory");
            __builtin_amdgcn_sched_barrier(0);
        } else {
            #pragma unroll
            for (int s = 0; s < 8; ++s)
                a[s] = (bf16x8){0, 0, 0, 0, 0, 0, 0, 0};
        }

        // ---- 24 MFMAs (weights + A in registers) ----
        floatx4 acc[3];
        #pragma unroll
        for (int g = 0; g < 3; ++g) acc[g] = (floatx4){0.f, 0.f, 0.f, 0.f};
        #pragma unroll
        for (int s = 0; s < 8; ++s)
            #pragma unroll
            for (int g = 0; g < 3; ++g)
                acc[g] = __builtin_amdgcn_mfma_f32_16x16x32_bf16(
                    a[s], wreg[g][s], acc[g], 0, 0, 0);

        #pragma unroll
        for (int g = 0; g < 3; ++g)
            part[wid][g][lane] = acc[g];     // ds_write_b128, conflict-free
        __syncthreads();

        // ---- cell updates (256 threads: b = tid>>4, j = tid&15) ----
        if (tid < 256) {
            float gh[3][3];
            #pragma unroll
            for (int mm = 0; mm < 3; ++mm)
                #pragma unroll
                for (int g = 0; g < 3; ++g)
                    gh[mm][g] = part[mm * 4 + 0][g][pl][pr] + part[mm * 4 + 1][g][pl][pr]
                              + part[mm * 4 + 2][g][pl][pr] + part[mm * 4 + 3][g][pl][pr];

            if (k < kT) {   // layer0 step t=k
                const float hr = gh[0][0] + b0r;
                const float hz = gh[0][1] + b0z;
                const float hn = gh[0][2] + b0n;
                const float r = 1.f / (1.f + __expf(-(gxr + hr)));
                const float z = 1.f / (1.f + __expf(-(gxz + hz)));
                const float n = tanhf(gxn + r * hn);
                const float hnew = (1.f - z) * n + z * h1reg;
                h1reg = hnew;
                store_short_sys(h1o + ub * kH + ujg, f2bf_fast_u(hnew));
            }
            if (k > 0) {    // layer1 step t=k-1; gx1 = gh[1] + b_ih1
                const float xr = gh[1][0] + b1r;
                const float xz = gh[1][1] + b1z;
                const float xn = gh[1][2] + b1n;
                const float hr = gh[2][0] + b2r;
                const float hz = gh[2][1] + b2z;
                const float hn = gh[2][2] + b2n;
                const float r = 1.f / (1.f + __expf(-(xr + hr)));
                const float z = 1.f / (1.f + __expf(-(xz + hz)));
                const float n = tanhf(xn + r * hn);
                const float hnew = (1.f - z) * n + z * h2reg;
                h2reg = hnew;
                store_short_sys(h2o + ub * kH + ujg, f2bf_fast_u(hnew));
                if (k == kT) h2last[(long)ub * kH + ujg] = hnew;  // fp32 for decoder
            }
        }

        // ---- prefetch gx0 for step k+1 (read-only; hides under barrier) ----
        float nxr = 0.f, nxz = 0.f, nxn = 0.f;
        if (tid < 256 && (k + 1) < kT) {
            const float* g = gx0 + (long)ub * (kT * 3 * kH) + (long)(k + 1) * 3 * kH;
            nxr = g[ujg]; nxz = g[kH + ujg]; nxn = g[2 * kH + ujg];
        }

        // ---- fence-free distributed-flag barrier (all state at L3) ----
        if (k < kT) {
            __syncthreads();          // per-wave vmcnt(0): sc-stores ACKed at L3
            if (wid == 0) {
                const unsigned gen = (unsigned)(k + 1);
                if (lane == 0)
                    store_dword_sys(&flags[bx * FLAG_STRIDE], gen);
                // lane i watches block i's flag
                while (load_dword_sys(&flags[lane * FLAG_STRIDE]) < gen) {}
            }
            __syncthreads();
        }

        gxr = nxr; gxz = nxz; gxn = nxn;
    }
}

// ---------------------------------------------------------------------------
// kernel_launch
// ---------------------------------------------------------------------------
extern "C" void kernel_launch(void* const* d_in, const int* in_sizes, int n_in,
                              void* d_out, int out_size, void* d_ws, size_t ws_size,
                              hipStream_t stream)
{
    const float* x        = (const float*)d_in[0];   // [16,64,4096]
    const float* w_ih_l0  = (const float*)d_in[1];   // [3072,4096]
    const float* w_hh_l0  = (const float*)d_in[2];   // [3072,1024]
    const float* b_ih_l0  = (const float*)d_in[3];   // [3072]
    const float* b_hh_l0  = (const float*)d_in[4];   // [3072]
    const float* w_ih_l1  = (const float*)d_in[5];   // [3072,1024]
    const float* w_hh_l1  = (const float*)d_in[6];   // [3072,1024]
    const float* b_ih_l1  = (const float*)d_in[7];   // [3072]
    const float* b_hh_l1  = (const float*)d_in[8];   // [3072]
    const float* dec_w    = (const float*)d_in[9];   // [4096,1024]
    const float* dec_b    = (const float*)d_in[10];  // [4096]
    float* out = (float*)d_out;                      // [16,4096]

    // Workspace (~62.5 MB): gx0 12 MB + 4 bf16 h-bufs 128 KB + h2last 64 KB
    // + 3 recurrence bf16 matrices 18 MB + xbf 8 MB + wihbf 24 MB + flags.
    float* ws    = (float*)d_ws;
    float* gx0   = ws;                                  // [1024,3072] rows b*T+t
    unsigned short* h1bf0 = (unsigned short*)(gx0 + (size_t)1024 * 3072);
    unsigned short* h1bf1 = h1bf0 + (size_t)kB * kH;
    unsigned short* h2bf0 = h1bf1 + (size_t)kB * kH;
    unsigned short* h2bf1 = h2bf0 + (size_t)kB * kH;
    float* h2last = (float*)(h2bf1 + (size_t)kB * kH);
    unsigned short* wbf0 = (unsigned short*)(h2last + (size_t)kB * kH);
    unsigned short* wbf1 = wbf0 + (size_t)3 * kH * kH;
    unsigned short* wbf2 = wbf1 + (size_t)3 * kH * kH;
    unsigned short* xbf  = wbf2 + (size_t)3 * kH * kH;          // [1024,4096]
    unsigned short* wihbf = xbf + (size_t)1024 * 4096;          // [3072,4096]
    unsigned* flags = (unsigned*)(wihbf + (size_t)3072 * 4096);

    // Flags must start at 0 each replay (memset node in the graph).
    (void)hipMemsetAsync(flags, 0, 4096, stream);

    const int wn4 = 3 * kH * kH / 4;           // 786432
    const int xn4 = 1024 * 4096 / 4;           // 1048576
    const int win4 = 3072 * 4096 / 4;          // 3145728

    // Pack recurrence weights + Phase-A operands fp32 -> bf16 (RNE)
    pack_bf16<<<(wn4 + 255) / 256, 256, 0, stream>>>(w_hh_l0, wbf0, wn4);
    pack_bf16<<<(wn4 + 255) / 256, 256, 0, stream>>>(w_ih_l1, wbf1, wn4);
    pack_bf16<<<(wn4 + 255) / 256, 256, 0, stream>>>(w_hh_l1, wbf2, wn4);
    pack_bf16<<<(xn4 + 255) / 256, 256, 0, stream>>>(x, xbf, xn4);
    pack_bf16<<<(win4 + 255) / 256, 256, 0, stream>>>(w_ih_l0, wihbf, win4);

    // Phase A (depth-2 pipelined bf16 MFMA): gx0 = x @ w_ih_l0^T + b_ih_l0
    // (M=1024, N=3072, K=4096), 64x128 tile, grid 384 (XCD-swizzled).
    gemm_bf16_a<<<384, 256, 0, stream>>>(
        xbf, wihbf, b_ih_l0, gx0, 1024, 3072, 4096);

    // Persistent fused recurrence: ONE launch, 65 in-kernel steps (v4).
    fused_gru_persistent<<<64, 768, 0, stream>>>(
        gx0, wbf0, b_hh_l0, wbf1, b_ih_l1, wbf2, b_hh_l1,
        h1bf0, h1bf1, h2bf0, h2bf1, h2last, flags);

    // Decoder (fp32): out = h2_last @ dec_w^T + dec_b  (M=16,N=4096,K=1024)
    gemm_nt_bias<<<dim3(4096 / GBN, 1), 256, 0, stream>>>(
        h2last, dec_w, dec_b, out, kB, 4096, 1024);
}

// Round 11
// 629.396 us; speedup vs baseline: 88.0647x; 1.0588x over previous
//
#include <hip/hip_runtime.h>
#include <math.h>

// Problem constants (B=16, T=64, NN=4096, H=1024)
constexpr int kB = 16;
constexpr int kT = 64;
constexpr int kH = 1024;

typedef short bf16x8 __attribute__((ext_vector_type(8)));   // 8 bf16 = 4 VGPR
typedef float floatx4 __attribute__((ext_vector_type(4)));  // MFMA acc

// ---------------------------------------------------------------------------
// bf16 convert helpers
// ---------------------------------------------------------------------------
__device__ __forceinline__ unsigned short f2bf_rne(float f) {
    unsigned u = __float_as_uint(f);
    u = u + 0x7FFFu + ((u >> 16) & 1u);
    return (unsigned short)(u >> 16);
}
__device__ __forceinline__ unsigned f2bf_fast_u(float f) {
    return (__float_as_uint(f) + 0x8000u) >> 16;
}

// ---------------------------------------------------------------------------
// System-scope (coherence-point) ops — v4 proven. sc0 sc1 = scope "system".
// (v6 lesson: sc0 alone is SE scope — NOT visible across the device.)
// ---------------------------------------------------------------------------
__device__ __forceinline__ void store_short_sys(unsigned short* p, unsigned v) {
    asm volatile("global_store_short %0, %1, off sc0 sc1"
                 :: "v"(p), "v"(v) : "memory");
}
__device__ __forceinline__ void store_dword_sys(unsigned* p, unsigned v) {
    asm volatile("global_store_dword %0, %1, off sc0 sc1"
                 :: "v"(p), "v"(v) : "memory");
}
__device__ __forceinline__ unsigned load_dword_sys(const unsigned* p) {
    unsigned v;
    asm volatile("global_load_dword %0, %1, off sc0 sc1\n\t"
                 "s_waitcnt vmcnt(0)"
                 : "=v"(v) : "v"(p) : "memory");
    return v;
}
// 3 independent sys-loads, one waitcnt (prefetch path; latency overlaps barrier)
__device__ __forceinline__ void load3_float_sys(const float* p0, const float* p1,
                                                const float* p2,
                                                float& a, float& b, float& c) {
    asm volatile("global_load_dword %0, %3, off sc0 sc1\n\t"
                 "global_load_dword %1, %4, off sc0 sc1\n\t"
                 "global_load_dword %2, %5, off sc0 sc1\n\t"
                 "s_waitcnt vmcnt(0)"
                 : "=&v"(a), "=&v"(b), "=&v"(c)
                 : "v"(p0), "v"(p1), "v"(p2) : "memory");
}

// async global->LDS, 16 B per lane. LDS dest is wave-uniform base; lanes
// land at base + lane*16. Global src is per-lane.
__device__ __forceinline__ void gload_lds16(const unsigned short* g,
                                            unsigned short* lds) {
    __builtin_amdgcn_global_load_lds(
        (const __attribute__((address_space(1))) unsigned int*)(g),
        (__attribute__((address_space(3))) unsigned int*)(lds), 16, 0, 0);
}

// ---------------------------------------------------------------------------
// Merged pack kernel: 5 fp32->bf16 (RNE) jobs in one launch.
// ---------------------------------------------------------------------------
__global__ __launch_bounds__(256)
void pack_bf16_multi(const float* __restrict__ s0, unsigned short* __restrict__ d0, int n0,
                     const float* __restrict__ s1, unsigned short* __restrict__ d1, int n1,
                     const float* __restrict__ s2, unsigned short* __restrict__ d2, int n2,
                     const float* __restrict__ s3, unsigned short* __restrict__ d3, int n3,
                     const float* __restrict__ s4, unsigned short* __restrict__ d4, int n4)
{
    int i = blockIdx.x * 256 + threadIdx.x;
    const float* s; unsigned short* d;
    if (i < n0) { s = s0; d = d0; }
    else { i -= n0;
    if (i < n1) { s = s1; d = d1; }
    else { i -= n1;
    if (i < n2) { s = s2; d = d2; }
    else { i -= n2;
    if (i < n3) { s = s3; d = d3; }
    else { i -= n3;
    if (i >= n4) return; s = s4; d = d4; }}}}
    const float4 v = ((const float4*)s)[i];
    ushort4 o;
    o.x = f2bf_rne(v.x); o.y = f2bf_rne(v.y);
    o.z = f2bf_rne(v.z); o.w = f2bf_rne(v.w);
    ((ushort4*)d)[i] = o;
}

// ---------------------------------------------------------------------------
// 64x64-tile fp32 GEMM (decoder only; M=16 guard): C = X@W^T + bias
// ---------------------------------------------------------------------------
#define GBM 64
#define GBN 64
#define GBK 16
#define GPAD 4

__global__ __launch_bounds__(256)
void gemm_nt_bias(const float* __restrict__ X, const float* __restrict__ W,
                  const float* __restrict__ bias, float* __restrict__ C,
                  int M, int N, int K)
{
    __shared__ float Xs[GBK][GBM + GPAD];
    __shared__ float Ws[GBK][GBN + GPAD];

    const int tid = threadIdx.x;
    const int bm = blockIdx.y * GBM;
    const int bn = blockIdx.x * GBN;
    const int tm = (tid >> 4) * 4;
    const int tn = (tid & 15) * 4;
    const int lr = tid >> 2;
    const int lc = (tid & 3) * 4;

    float acc[4][4] = {};

    for (int k0 = 0; k0 < K; k0 += GBK) {
        {
            const int gr = bm + lr;
            float4 v = make_float4(0.f, 0.f, 0.f, 0.f);
            if (gr < M) v = *(const float4*)(X + (long)gr * K + k0 + lc);
            Xs[lc + 0][lr] = v.x; Xs[lc + 1][lr] = v.y;
            Xs[lc + 2][lr] = v.z; Xs[lc + 3][lr] = v.w;
        }
        {
            const int gr = bn + lr;
            const float4 v = *(const float4*)(W + (long)gr * K + k0 + lc);
            Ws[lc + 0][lr] = v.x; Ws[lc + 1][lr] = v.y;
            Ws[lc + 2][lr] = v.z; Ws[lc + 3][lr] = v.w;
        }
        __syncthreads();
        #pragma unroll
        for (int k = 0; k < GBK; ++k) {
            const float4 a4 = *(const float4*)&Xs[k][tm];
            const float4 b4 = *(const float4*)&Ws[k][tn];
            acc[0][0] += a4.x * b4.x; acc[0][1] += a4.x * b4.y; acc[0][2] += a4.x * b4.z; acc[0][3] += a4.x * b4.w;
            acc[1][0] += a4.y * b4.x; acc[1][1] += a4.y * b4.y; acc[1][2] += a4.y * b4.z; acc[1][3] += a4.y * b4.w;
            acc[2][0] += a4.z * b4.x; acc[2][1] += a4.z * b4.y; acc[2][2] += a4.z * b4.z; acc[2][3] += a4.z * b4.w;
            acc[3][0] += a4.w * b4.x; acc[3][1] += a4.w * b4.y; acc[3][2] += a4.w * b4.z; acc[3][3] += a4.w * b4.w;
        }
        __syncthreads();
    }

    #pragma unroll
    for (int i = 0; i < 4; ++i) {
        const int gr = bm + tm + i;
        if (gr >= M) continue;
        #pragma unroll
        for (int jj = 0; jj < 4; ++jj) {
            const int gc = bn + tn + jj;
            C[(long)gr * N + gc] = acc[i][jj] + bias[gc];
        }
    }
}

// ---------------------------------------------------------------------------
// MEGA-KERNEL v7: recurrence (blocks 0..63, v4-verbatim) + Phase-A GEMM
// workers (blocks 64..255) OVERLAPPED in one launch.
//
// Workers: 384 tiles of gx0, each = t-chunk(4 timesteps x 16 batches,
// row-gathered) x 128 cols x K=4096. Chunk-major order: pass 1 (tiles
// 0..191) covers t-chunks 0..7, pass 2 covers 8..15. Per tile: depth-2
// gload_lds ring (1 issue/wave/tile, 12 waves = A:4 + B:8 issues),
// counted vmcnt(2), 8 MFMA waves (2x2 frags each). Epilogue: sys-store
// gx0 + vmcnt(0) + barrier + sys-store tile flag — IDENTICAL visibility
// chain to the proven v4 h-exchange.
//
// Recurrence: v4 + per-chunk gx0 gating (one flag poll per 4 steps,
// cached; usually already set) and sys-loads for gx0 (fresh at the
// coherence point; avoids first-run stale-prefetch hazard).
// Deadlock-free: workers never wait; all 256 blocks resident (48KB LDS).
// ---------------------------------------------------------------------------
#define FLAG_STRIDE 4   // uints; 16 B between recurrence flags

__global__ __launch_bounds__(768, 3)
void fused_mega(const unsigned short* __restrict__ xbf,    // [1024,4096] bf16
                const unsigned short* __restrict__ wihbf,  // [3072,4096] bf16
                const float* __restrict__ bih0,            // [3072]
                float* __restrict__ gx0,                   // [1024,3072]
                const unsigned short* __restrict__ w0, const float* __restrict__ bb0,
                const unsigned short* __restrict__ w1, const float* __restrict__ bb1,
                const unsigned short* __restrict__ w2, const float* __restrict__ bb2,
                unsigned short* __restrict__ h1bf0, unsigned short* __restrict__ h1bf1,
                unsigned short* __restrict__ h2bf0, unsigned short* __restrict__ h2bf1,
                float* __restrict__ h2last, unsigned* __restrict__ flags)
{
    __shared__ __attribute__((aligned(16))) char smem[49152];  // union, 48 KB

    const int tid = threadIdx.x;     // 0..767
    const int bx  = blockIdx.x;
    const int lane = tid & 63;
    const int wid  = tid >> 6;       // 0..11
    unsigned* const gxflags = flags + 256;   // 384 uints: [chunk*24 + ntile]

    if (bx >= 64) {
        // =================== GEMM WORKER ===================
        unsigned short (*As)[2048] = (unsigned short(*)[2048])smem;            // [4][64*32]
        unsigned short (*Bs)[4096] = (unsigned short(*)[4096])(smem + 16384);  // [4][128*32]
        const int widx = bx - 64;            // 0..191
        const int srow = lane >> 2;          // 0..15
        const int scol = (lane & 3) * 8;     // 0,8,16,24
        const int al = lane & 15;
        const int aq = lane >> 4;
        const int wm = wid & 1;              // MFMA waves (wid<8): 32-row half
        const int wn = wid >> 1;             // 0..3: 32-col quarter

        for (int pass = 0; pass < 2; ++pass) {
            const int T = widx + pass * 192;     // 0..383
            const int c = T / 24;                // t-chunk 0..15
            const int n = T % 24;                // N-tile
            const int bn = n * 128;

            // per-wave staging source (1 gload_lds issue per wave per K-step)
            const unsigned short* gsrc;
            int ldsoff;          // element offset inside A/B buffer
            bool isA;
            if (wid < 4) {       // A issues: tile-rows wid*16 + srow (gathered)
                const int tr = wid * 16 + srow;
                const long grow = (long)((tr >> 2) * 64 + c * 4 + (tr & 3));
                gsrc = xbf + grow * 4096 + scol;
                ldsoff = wid * 512;
                isA = true;
            } else {             // B issues: rows bn + (wid-4)*16 + srow
                gsrc = wihbf + (long)(bn + (wid - 4) * 16 + srow) * 4096 + scol;
                ldsoff = (wid - 4) * 512;
                isA = false;
            }

            floatx4 acc[2][2];
            #pragma unroll
            for (int i = 0; i < 2; ++i)
                #pragma unroll
                for (int j = 0; j < 2; ++j)
                    acc[i][j] = (floatx4){0.f, 0.f, 0.f, 0.f};

            // prologue: tiles 0,1 in flight
            if (isA) { gload_lds16(gsrc + 0,  &As[0][ldsoff]);
                       gload_lds16(gsrc + 32, &As[1][ldsoff]); }
            else     { gload_lds16(gsrc + 0,  &Bs[0][ldsoff]);
                       gload_lds16(gsrc + 32, &Bs[1][ldsoff]); }

            for (int t = 0; t < 128; ++t) {
                const int k2 = (t + 2 < 128) ? (t + 2) * 32 : t * 32;  // dummy tail
                const int b2 = (t + 2) & 3;
                if (isA) gload_lds16(gsrc + k2, &As[b2][ldsoff]);
                else     gload_lds16(gsrc + k2, &Bs[b2][ldsoff]);

                asm volatile("s_waitcnt vmcnt(2)" ::: "memory");  // tile t ready
                __builtin_amdgcn_s_barrier();
                asm volatile("" ::: "memory");

                if (wid < 8) {
                    const int cb = t & 3;
                    bf16x8 af[2], bfr[2];
                    #pragma unroll
                    for (int i = 0; i < 2; ++i)
                        af[i] = *(const bf16x8*)&As[cb][(wm * 32 + i * 16 + al) * 32 + aq * 8];
                    #pragma unroll
                    for (int j = 0; j < 2; ++j)
                        bfr[j] = *(const bf16x8*)&Bs[cb][(wn * 32 + j * 16 + al) * 32 + aq * 8];
                    #pragma unroll
                    for (int i = 0; i < 2; ++i)
                        #pragma unroll
                        for (int j = 0; j < 2; ++j)
                            acc[i][j] = __builtin_amdgcn_mfma_f32_16x16x32_bf16(
                                af[i], bfr[j], acc[i][j], 0, 0, 0);
                }
                asm volatile("" ::: "memory");
                __builtin_amdgcn_s_barrier();
            }

            // epilogue: publish gx0 (sys-stores) + flag — v4 visibility chain
            if (wid < 8) {
                #pragma unroll
                for (int i = 0; i < 2; ++i) {
                    #pragma unroll
                    for (int j = 0; j < 2; ++j) {
                        const int col = bn + wn * 32 + j * 16 + al;
                        const float bv = bih0[col];
                        #pragma unroll
                        for (int r = 0; r < 4; ++r) {
                            const int tr = wm * 32 + i * 16 + aq * 4 + r;
                            const long g = (long)((tr >> 2) * 64 + c * 4 + (tr & 3));
                            store_dword_sys((unsigned*)&gx0[g * 3072 + col],
                                            __float_as_uint(acc[i][j][r] + bv));
                        }
                    }
                }
            }
            asm volatile("s_waitcnt vmcnt(0)" ::: "memory");  // stores ACKed at L3
            __builtin_amdgcn_s_barrier();                     // all waves' stores done
            if (tid == 0) store_dword_sys(&gxflags[c * 24 + n], 1u);
        }
        return;
    }

    // =================== RECURRENCE (v4 + gx0 gating) ===================
    floatx4 (*part)[3][64] = (floatx4(*)[3][64])smem;   // [12][3][64], 36 KB

    const int jbase = bx * 16;
    const int ntile = bx >> 3;         // which gx0 N-tile covers our 16 cols

    const int m  = wid >> 2;           // matrix: 0 w_hh0, 1 w_ih1, 2 w_hh1
    const int kh = wid & 3;            // K-quarter
    const int al = lane & 15;
    const int aq = lane >> 4;

    // ---- one-time: weight fragments -> registers ----
    const unsigned short* Wm = (m == 0) ? w0 : (m == 1) ? w1 : w2;
    const long wbase = (long)(jbase + al) * kH + kh * 256 + aq * 8;
    bf16x8 wreg[3][8];
    #pragma unroll
    for (int g = 0; g < 3; ++g)
        #pragma unroll
        for (int s = 0; s < 8; ++s)
            wreg[g][s] = *(const bf16x8*)(Wm + (long)g * kH * kH + wbase + s * 32);

    // ---- one-time: update-phase bias preload (tid<256 only) ----
    const int ub  = tid >> 4;          // batch row for update phase
    const int ujj = tid & 15;
    const int ujg = jbase + ujj;
    const float b0r = bb0[ujg], b0z = bb0[kH + ujg], b0n = bb0[2 * kH + ujg];
    const float b1r = bb1[ujg], b1z = bb1[kH + ujg], b1n = bb1[2 * kH + ujg];
    const float b2r = bb2[ujg], b2z = bb2[kH + ujg], b2n = bb2[2 * kH + ujg];

    float h1reg = 0.f;   // h1_{k-1} for this (b,j)
    float h2reg = 0.f;   // h2_{k-2} for this (b,j)

    const int aoff = al * kH + kh * 256 + aq * 8;
    const int pl   = (ub >> 2) * 16 + ujj;
    const int pr   = ub & 3;

    // gx0 for step 0: gate on chunk 0, then sys-load
    float gxr = 0.f, gxz = 0.f, gxn = 0.f;
    int readyChunk = -1;
    if (tid < 256) {
        while (load_dword_sys(&gxflags[0 * 24 + ntile]) == 0) {}
        readyChunk = 0;
        const float* g = gx0 + (long)ub * (kT * 3 * kH);
        load3_float_sys(g + ujg, g + kH + ujg, g + 2 * kH + ujg, gxr, gxz, gxn);
    }

    for (int k = 0; k <= kT; ++k) {
        const unsigned short* h1p = (k & 1) ? h1bf0 : h1bf1;   // h1_{k-1}
        unsigned short*       h1o = (k & 1) ? h1bf1 : h1bf0;   // h1_k
        const unsigned short* h2p = (k & 1) ? h2bf1 : h2bf0;   // h2_{k-2}
        unsigned short*       h2o = (k & 1) ? h2bf0 : h2bf1;   // h2_{k-1}

        // ---- A-fragments: system-scope loads from the bf16 h buffers ----
        const bool azero = (m < 2) ? (k == 0) : (k <= 1);
        const unsigned short* hsrc = (m < 2) ? h1p : h2p;
        bf16x8 a[8];
        if (!azero) {
            #pragma unroll
            for (int s = 0; s < 8; ++s)
                asm volatile("global_load_dwordx4 %0, %1, off sc0 sc1"
                             : "=&v"(a[s]) : "v"(hsrc + aoff + s * 32) : "memory");
            asm volatile("s_waitcnt vmcnt(0)" ::: "memory");
            __builtin_amdgcn_sched_barrier(0);
        } else {
            #pragma unroll
            for (int s = 0; s < 8; ++s)
                a[s] = (bf16x8){0, 0, 0, 0, 0, 0, 0, 0};
        }

        // ---- 24 MFMAs (weights + A in registers) ----
        floatx4 acc[3];
        #pragma unroll
        for (int g = 0; g < 3; ++g) acc[g] = (floatx4){0.f, 0.f, 0.f, 0.f};
        #pragma unroll
        for (int s = 0; s < 8; ++s)
            #pragma unroll
            for (int g = 0; g < 3; ++g)
                acc[g] = __builtin_amdgcn_mfma_f32_16x16x32_bf16(
                    a[s], wreg[g][s], acc[g], 0, 0, 0);

        #pragma unroll
        for (int g = 0; g < 3; ++g)
            part[wid][g][lane] = acc[g];     // ds_write_b128, conflict-free
        __syncthreads();

        // ---- cell updates (256 threads: b = tid>>4, j = tid&15) ----
        if (tid < 256) {
            float gh[3][3];
            #pragma unroll
            for (int mm = 0; mm < 3; ++mm)
                #pragma unroll
                for (int g = 0; g < 3; ++g)
                    gh[mm][g] = part[mm * 4 + 0][g][pl][pr] + part[mm * 4 + 1][g][pl][pr]
                              + part[mm * 4 + 2][g][pl][pr] + part[mm * 4 + 3][g][pl][pr];

            if (k < kT) {   // layer0 step t=k
                const float hr = gh[0][0] + b0r;
                const float hz = gh[0][1] + b0z;
                const float hn = gh[0][2] + b0n;
                const float r = 1.f / (1.f + __expf(-(gxr + hr)));
                const float z = 1.f / (1.f + __expf(-(gxz + hz)));
                const float n = tanhf(gxn + r * hn);
                const float hnew = (1.f - z) * n + z * h1reg;
                h1reg = hnew;
                store_short_sys(h1o + ub * kH + ujg, f2bf_fast_u(hnew));
            }
            if (k > 0) {    // layer1 step t=k-1; gx1 = gh[1] + b_ih1
                const float xr = gh[1][0] + b1r;
                const float xz = gh[1][1] + b1z;
                const float xn = gh[1][2] + b1n;
                const float hr = gh[2][0] + b2r;
                const float hz = gh[2][1] + b2z;
                const float hn = gh[2][2] + b2n;
                const float r = 1.f / (1.f + __expf(-(xr + hr)));
                const float z = 1.f / (1.f + __expf(-(xz + hz)));
                const float n = tanhf(xn + r * hn);
                const float hnew = (1.f - z) * n + z * h2reg;
                h2reg = hnew;
                store_short_sys(h2o + ub * kH + ujg, f2bf_fast_u(hnew));
                if (k == kT) h2last[(long)ub * kH + ujg] = hnew;  // fp32 for decoder
            }
        }

        // ---- prefetch gx0 for step k+1 (gated per chunk; hides under barrier) ----
        float nxr = 0.f, nxz = 0.f, nxn = 0.f;
        if (tid < 256 && (k + 1) < kT) {
            const int c2 = (k + 1) >> 2;
            if (c2 != readyChunk) {
                while (load_dword_sys(&gxflags[c2 * 24 + ntile]) == 0) {}
                readyChunk = c2;
            }
            const float* g = gx0 + (long)ub * (kT * 3 * kH) + (long)(k + 1) * 3 * kH;
            load3_float_sys(g + ujg, g + kH + ujg, g + 2 * kH + ujg, nxr, nxz, nxn);
        }

        // ---- distributed-flag all-poll barrier (v4, proven) ----
        if (k < kT) {
            __syncthreads();          // per-wave vmcnt(0): sc-stores ACKed at L3
            if (wid == 0) {
                const unsigned gen = (unsigned)(k + 1);
                if (lane == 0)
                    store_dword_sys(&flags[bx * FLAG_STRIDE], gen);
                while (load_dword_sys(&flags[lane * FLAG_STRIDE]) < gen) {}
            }
            __syncthreads();
        }

        gxr = nxr; gxz = nxz; gxn = nxn;
    }
}

// ---------------------------------------------------------------------------
// kernel_launch
// ---------------------------------------------------------------------------
extern "C" void kernel_launch(void* const* d_in, const int* in_sizes, int n_in,
                              void* d_out, int out_size, void* d_ws, size_t ws_size,
                              hipStream_t stream)
{
    const float* x        = (const float*)d_in[0];   // [16,64,4096]
    const float* w_ih_l0  = (const float*)d_in[1];   // [3072,4096]
    const float* w_hh_l0  = (const float*)d_in[2];   // [3072,1024]
    const float* b_ih_l0  = (const float*)d_in[3];   // [3072]
    const float* b_hh_l0  = (const float*)d_in[4];   // [3072]
    const float* w_ih_l1  = (const float*)d_in[5];   // [3072,1024]
    const float* w_hh_l1  = (const float*)d_in[6];   // [3072,1024]
    const float* b_ih_l1  = (const float*)d_in[7];   // [3072]
    const float* b_hh_l1  = (const float*)d_in[8];   // [3072]
    const float* dec_w    = (const float*)d_in[9];   // [4096,1024]
    const float* dec_b    = (const float*)d_in[10];  // [4096]
    float* out = (float*)d_out;                      // [16,4096]

    // Workspace (~62.5 MB): gx0 12 MB + 4 bf16 h-bufs 128 KB + h2last 64 KB
    // + 3 recurrence bf16 matrices 18 MB + xbf 8 MB + wihbf 24 MB + flags.
    float* ws    = (float*)d_ws;
    float* gx0   = ws;                                  // [1024,3072] rows b*T+t
    unsigned short* h1bf0 = (unsigned short*)(gx0 + (size_t)1024 * 3072);
    unsigned short* h1bf1 = h1bf0 + (size_t)kB * kH;
    unsigned short* h2bf0 = h1bf1 + (size_t)kB * kH;
    unsigned short* h2bf1 = h2bf0 + (size_t)kB * kH;
    float* h2last = (float*)(h2bf1 + (size_t)kB * kH);
    unsigned short* wbf0 = (unsigned short*)(h2last + (size_t)kB * kH);
    unsigned short* wbf1 = wbf0 + (size_t)3 * kH * kH;
    unsigned short* wbf2 = wbf1 + (size_t)3 * kH * kH;
    unsigned short* xbf  = wbf2 + (size_t)3 * kH * kH;          // [1024,4096]
    unsigned short* wihbf = xbf + (size_t)1024 * 4096;          // [3072,4096]
    unsigned* flags = (unsigned*)(wihbf + (size_t)3072 * 4096);

    // flags[0..255]: recurrence barrier; flags[256..639]: gx0 tile flags.
    (void)hipMemsetAsync(flags, 0, 4096, stream);

    const int wn4 = 3 * kH * kH / 4;           // 786432
    const int xn4 = 1024 * 4096 / 4;           // 1048576
    const int win4 = 3072 * 4096 / 4;          // 3145728
    const int total4 = wn4 * 3 + xn4 + win4;   // 6553600

    // ONE merged pack launch (5 jobs)
    pack_bf16_multi<<<(total4 + 255) / 256, 256, 0, stream>>>(
        w_hh_l0, wbf0, wn4,  w_ih_l1, wbf1, wn4,  w_hh_l1, wbf2, wn4,
        x, xbf, xn4,  w_ih_l0, wihbf, win4);

    // MEGA: Phase-A workers (192 blocks) overlapped with the persistent
    // recurrence (64 blocks). Single launch.
    fused_mega<<<256, 768, 0, stream>>>(
        xbf, wihbf, b_ih_l0, gx0,
        wbf0, b_hh_l0, wbf1, b_ih_l1, wbf2, b_hh_l1,
        h1bf0, h1bf1, h2bf0, h2bf1, h2last, flags);

    // Decoder (fp32): out = h2_last @ dec_w^T + dec_b  (M=16,N=4096,K=1024)
    gemm_nt_bias<<<dim3(4096 / GBN, 1), 256, 0, stream>>>(
        h2last, dec_w, dec_b, out, kB, 4096, 1024);
}